// Round 1
// baseline (4486.680 us; speedup 1.0000x reference)
//
#include <hip/hip_runtime.h>
#include <hip/hip_bf16.h>
#include <stdint.h>

#define NROWS 65536
#define INDIM 768
#define ODIM  256
#define NLEV  4
#define CBS   1024
#define TAU   1e-2f   // top-2 gap threshold for f64 re-check (f32 error budget ~1e-4, 100x margin)

__device__ __forceinline__ float bf2f(unsigned short u) {
    union { unsigned int i; float f; } v; v.i = ((unsigned int)u) << 16; return v.f;
}
__device__ __forceinline__ unsigned short f2bf(float f) {
    union { float f; unsigned int i; } v; v.f = f;
    unsigned int r = v.i + 0x7fffu + ((v.i >> 16) & 1u);
    return (unsigned short)(r >> 16);
}

__global__ void k_init(double* __restrict__ acc) {
    if (threadIdx.x < 2) acc[threadIdx.x] = 0.0;
}

// ||c||^2 per codebook row
__global__ __launch_bounds__(64) void k_cnorm(const float* __restrict__ cb, float* __restrict__ cn) {
    const int code = blockIdx.x;
    const float* r = cb + (size_t)code * ODIM + threadIdx.x * 4;
    float4 v = *(const float4*)r;
    float s = fmaf(v.x, v.x, fmaf(v.y, v.y, fmaf(v.z, v.z, v.w * v.w)));
    #pragma unroll
    for (int o = 32; o > 0; o >>= 1) s += __shfl_xor(s, o);
    if (threadIdx.x == 0) cn[code] = s;
}

// per-row mean / rsqrt(var+eps)
__global__ __launch_bounds__(256) void k_ln(const float* __restrict__ x,
                                            float* __restrict__ mu, float* __restrict__ rsig) {
    const int row = blockIdx.x;
    const int t = threadIdx.x;
    const float* xr = x + (size_t)row * INDIM;
    float a = xr[t], b = xr[t + 256], c = xr[t + 512];
    float s1 = a + b + c;
    float s2 = fmaf(a, a, fmaf(b, b, c * c));
    #pragma unroll
    for (int o = 32; o > 0; o >>= 1) { s1 += __shfl_xor(s1, o); s2 += __shfl_xor(s2, o); }
    __shared__ float r1[4], r2[4];
    if ((t & 63) == 0) { r1[t >> 6] = s1; r2[t >> 6] = s2; }
    __syncthreads();
    if (t == 0) {
        float S1 = (r1[0] + r1[1]) + (r1[2] + r1[3]);
        float S2 = (r2[0] + r2[1]) + (r2[2] + r2[3]);
        float m = S1 * (1.0f / INDIM);
        float var = S2 * (1.0f / INDIM) - m * m;
        mu[row] = m;
        rsig[row] = rsqrtf(var + 1e-5f);
    }
}

// C[M,Nc] = op(A[M,K]) @ B[K,Nc] + bias.  Tiles: 64(M) x 128(N) x 16(K), 256 thr, 4x8 acc.
// AMODE: 0 plain f32 A, 1 LayerNorm-on-load (A=x), 2 bf16 A
// EPI:   0 relu->f32, 1 f32, 2 relu->bf16, 3 f32 + sum((C-xref)^2) into acc_rec
template <int AMODE, int EPI>
__global__ __launch_bounds__(256) void k_gemm(
    const void* __restrict__ Ap, const float* __restrict__ B,
    const float* __restrict__ bias, void* __restrict__ Cp,
    const int K, const int Nc,
    const float* __restrict__ mu, const float* __restrict__ rsig,
    const float* __restrict__ lng, const float* __restrict__ lnb,
    const float* __restrict__ xref, double* __restrict__ acc_rec)
{
    __shared__ float At[16 * 64];    // [k][m]
    __shared__ float Bt[16 * 128];   // [k][n]
    __shared__ float red[4];
    float acc[4][8];
    #pragma unroll
    for (int i = 0; i < 4; ++i)
        #pragma unroll
        for (int j = 0; j < 8; ++j) acc[i][j] = 0.0f;

    const int t = threadIdx.x;
    const int tx = t & 15, ty = t >> 4;
    const size_t bm = (size_t)blockIdx.y * 64;
    const int bn = blockIdx.x * 128;
    const int lm = t >> 2, lk = (t & 3) << 2;
    const int bk = t >> 4, bnn = (t & 15) << 3;
    float lnm = 0.f, lnr = 0.f;
    if (AMODE == 1) { lnm = mu[bm + lm]; lnr = rsig[bm + lm]; }

    for (int kk = 0; kk < K; kk += 16) {
        float4 av;
        if (AMODE == 0) {
            av = *(const float4*)((const float*)Ap + (bm + lm) * (size_t)K + kk + lk);
        } else if (AMODE == 1) {
            float4 xv = *(const float4*)((const float*)Ap + (bm + lm) * (size_t)K + kk + lk);
            float4 g  = *(const float4*)(lng + kk + lk);
            float4 bb = *(const float4*)(lnb + kk + lk);
            av.x = fmaf((xv.x - lnm) * lnr, g.x, bb.x);
            av.y = fmaf((xv.y - lnm) * lnr, g.y, bb.y);
            av.z = fmaf((xv.z - lnm) * lnr, g.z, bb.z);
            av.w = fmaf((xv.w - lnm) * lnr, g.w, bb.w);
        } else {
            ushort4 uv = *(const ushort4*)((const unsigned short*)Ap + (bm + lm) * (size_t)K + kk + lk);
            av.x = bf2f(uv.x); av.y = bf2f(uv.y); av.z = bf2f(uv.z); av.w = bf2f(uv.w);
        }
        float4 bv0 = *(const float4*)(B + (size_t)(kk + bk) * Nc + bn + bnn);
        float4 bv1 = *(const float4*)(B + (size_t)(kk + bk) * Nc + bn + bnn + 4);
        __syncthreads();
        At[(lk + 0) * 64 + lm] = av.x;
        At[(lk + 1) * 64 + lm] = av.y;
        At[(lk + 2) * 64 + lm] = av.z;
        At[(lk + 3) * 64 + lm] = av.w;
        *(float4*)&Bt[bk * 128 + bnn] = bv0;
        *(float4*)&Bt[bk * 128 + bnn + 4] = bv1;
        __syncthreads();
        #pragma unroll
        for (int k = 0; k < 16; ++k) {
            float a[4], b[8];
            *(float4*)a = *(float4*)&At[k * 64 + (ty << 2)];
            *(float4*)&b[0] = *(float4*)&Bt[k * 128 + (tx << 2)];
            *(float4*)&b[4] = *(float4*)&Bt[k * 128 + 64 + (tx << 2)];
            #pragma unroll
            for (int i = 0; i < 4; ++i)
                #pragma unroll
                for (int j = 0; j < 8; ++j)
                    acc[i][j] = fmaf(a[i], b[j], acc[i][j]);
        }
    }

    const int col0 = bn + (tx << 2);
    float4 bs0 = *(const float4*)(bias + col0);
    float4 bs1 = *(const float4*)(bias + col0 + 64);
    float lsum = 0.0f;
    #pragma unroll
    for (int i = 0; i < 4; ++i) {
        const size_t row = bm + (ty << 2) + i;
        float v[8];
        v[0] = acc[i][0] + bs0.x; v[1] = acc[i][1] + bs0.y;
        v[2] = acc[i][2] + bs0.z; v[3] = acc[i][3] + bs0.w;
        v[4] = acc[i][4] + bs1.x; v[5] = acc[i][5] + bs1.y;
        v[6] = acc[i][6] + bs1.z; v[7] = acc[i][7] + bs1.w;
        if (EPI == 0 || EPI == 2) {
            #pragma unroll
            for (int j = 0; j < 8; ++j) v[j] = fmaxf(v[j], 0.0f);
        }
        if (EPI == 2) {
            unsigned short* crow = (unsigned short*)Cp + row * Nc + col0;
            *(ushort4*)crow        = make_ushort4(f2bf(v[0]), f2bf(v[1]), f2bf(v[2]), f2bf(v[3]));
            *(ushort4*)(crow + 64) = make_ushort4(f2bf(v[4]), f2bf(v[5]), f2bf(v[6]), f2bf(v[7]));
        } else {
            float* crow = (float*)Cp + row * Nc + col0;
            *(float4*)crow        = make_float4(v[0], v[1], v[2], v[3]);
            *(float4*)(crow + 64) = make_float4(v[4], v[5], v[6], v[7]);
        }
        if (EPI == 3) {
            const float* xr = xref + row * INDIM + col0;
            float4 x0 = *(const float4*)xr;
            float4 x1 = *(const float4*)(xr + 64);
            float d;
            d = v[0] - x0.x; lsum = fmaf(d, d, lsum);
            d = v[1] - x0.y; lsum = fmaf(d, d, lsum);
            d = v[2] - x0.z; lsum = fmaf(d, d, lsum);
            d = v[3] - x0.w; lsum = fmaf(d, d, lsum);
            d = v[4] - x1.x; lsum = fmaf(d, d, lsum);
            d = v[5] - x1.y; lsum = fmaf(d, d, lsum);
            d = v[6] - x1.z; lsum = fmaf(d, d, lsum);
            d = v[7] - x1.w; lsum = fmaf(d, d, lsum);
        }
    }
    if (EPI == 3) {
        #pragma unroll
        for (int o = 32; o > 0; o >>= 1) lsum += __shfl_xor(lsum, o);
        if ((t & 63) == 0) red[t >> 6] = lsum;
        __syncthreads();
        if (t == 0) atomicAdd(acc_rec, (double)((red[0] + red[1]) + (red[2] + red[3])));
    }
}

// Fused 4-level residual quantization for a 64-row tile.
// Writes: indices (float) to oidx, q_final to qf, residual scratch, commit sum (atomic),
// per-row "near-tie" flag for the f64 fixup pass.
__global__ __launch_bounds__(256) void k_quant(
    const float* __restrict__ enc, const float* __restrict__ cb,
    const float* __restrict__ cnorm, float* __restrict__ resid,
    float* __restrict__ qf, float* __restrict__ oidx,
    int* __restrict__ flag, double* __restrict__ acc_commit)
{
    __shared__ float ct[16 * 256];   // [k][code]
    __shared__ float rt[16 * 64];    // [k][row]
    __shared__ float mval[64 * 17];
    __shared__ int   midx[64 * 17];
    __shared__ float m2v[64 * 17];
    __shared__ int   rowidx[64];
    __shared__ float cred[4];

    const int t = threadIdx.x;
    const int tx = t & 15, ty = t >> 4;
    const size_t bm = (size_t)blockIdx.x * 64;
    const int lrow = t >> 2, lq = t & 3;
    float commit_local = 0.0f;
    int flagreg = 0;

    for (int l = 0; l < NLEV; ++l) {
        const float* src = (l == 0) ? enc : (const float*)resid;
        const float* cbl = cb + (size_t)l * CBS * ODIM;
        const float* cnl = cnorm + l * CBS;
        float bestv[4], b2v[4];
        int besti[4];
        #pragma unroll
        for (int i = 0; i < 4; ++i) { bestv[i] = 3.4e38f; b2v[i] = 3.4e38f; besti[i] = 0; }

        for (int cc = 0; cc < 4; ++cc) {
            const int cbase = cc << 8;
            float acc[4][16];
            #pragma unroll
            for (int i = 0; i < 4; ++i)
                #pragma unroll
                for (int j = 0; j < 16; ++j) acc[i][j] = 0.0f;

            for (int kk = 0; kk < ODIM; kk += 16) {
                float4 rv = *(const float4*)(src + (bm + lrow) * ODIM + kk + (lq << 2));
                const float* cs = cbl + (size_t)(cbase + t) * ODIM + kk;
                float4 c0 = *(const float4*)(cs);
                float4 c1 = *(const float4*)(cs + 4);
                float4 c2 = *(const float4*)(cs + 8);
                float4 c3 = *(const float4*)(cs + 12);
                __syncthreads();
                rt[((lq << 2) + 0) * 64 + lrow] = rv.x;
                rt[((lq << 2) + 1) * 64 + lrow] = rv.y;
                rt[((lq << 2) + 2) * 64 + lrow] = rv.z;
                rt[((lq << 2) + 3) * 64 + lrow] = rv.w;
                ct[ 0 * 256 + t] = c0.x; ct[ 1 * 256 + t] = c0.y; ct[ 2 * 256 + t] = c0.z; ct[ 3 * 256 + t] = c0.w;
                ct[ 4 * 256 + t] = c1.x; ct[ 5 * 256 + t] = c1.y; ct[ 6 * 256 + t] = c1.z; ct[ 7 * 256 + t] = c1.w;
                ct[ 8 * 256 + t] = c2.x; ct[ 9 * 256 + t] = c2.y; ct[10 * 256 + t] = c2.z; ct[11 * 256 + t] = c2.w;
                ct[12 * 256 + t] = c3.x; ct[13 * 256 + t] = c3.y; ct[14 * 256 + t] = c3.z; ct[15 * 256 + t] = c3.w;
                __syncthreads();
                #pragma unroll
                for (int k = 0; k < 16; ++k) {
                    float a[4], b[16];
                    *(float4*)a = *(float4*)&rt[k * 64 + (ty << 2)];
                    *(float4*)&b[0]  = *(float4*)&ct[k * 256 +       (tx << 2)];
                    *(float4*)&b[4]  = *(float4*)&ct[k * 256 +  64 + (tx << 2)];
                    *(float4*)&b[8]  = *(float4*)&ct[k * 256 + 128 + (tx << 2)];
                    *(float4*)&b[12] = *(float4*)&ct[k * 256 + 192 + (tx << 2)];
                    #pragma unroll
                    for (int i = 0; i < 4; ++i)
                        #pragma unroll
                        for (int j = 0; j < 16; ++j)
                            acc[i][j] = fmaf(a[i], b[j], acc[i][j]);
                }
            }
            #pragma unroll
            for (int j = 0; j < 16; ++j) {
                const int code = cbase + ((j >> 2) << 6) + (tx << 2) + (j & 3);
                const float cn = cnl[code];
                #pragma unroll
                for (int i = 0; i < 4; ++i) {
                    const float d = fmaf(-2.0f, acc[i][j], cn);
                    if (d < bestv[i]) { b2v[i] = bestv[i]; bestv[i] = d; besti[i] = code; }
                    else { b2v[i] = fminf(b2v[i], d); }
                }
            }
        }
        __syncthreads();
        #pragma unroll
        for (int i = 0; i < 4; ++i) {
            mval[((ty << 2) + i) * 17 + tx] = bestv[i];
            midx[((ty << 2) + i) * 17 + tx] = besti[i];
            m2v [((ty << 2) + i) * 17 + tx] = b2v[i];
        }
        __syncthreads();
        if (t < 64) {
            float bv = mval[t * 17]; int bi = midx[t * 17]; float b2 = m2v[t * 17];
            #pragma unroll
            for (int j = 1; j < 16; ++j) {
                float v = mval[t * 17 + j]; int ii = midx[t * 17 + j]; float v2 = m2v[t * 17 + j];
                if (v < bv)      { b2 = fminf(bv, v2); bv = v; bi = ii; }
                else if (v > bv) { b2 = fminf(b2, v); }
                else             { b2 = bv; bi = (ii < bi) ? ii : bi; }
            }
            rowidx[t] = bi;
            oidx[(bm + t) * NLEV + l] = (float)bi;
            flagreg |= (b2 - bv < TAU) ? 1 : 0;
        }
        __syncthreads();
        {
            const float* crow = cbl + (size_t)rowidx[lrow] * ODIM + (lq << 6);
            const float* srow = src + (bm + lrow) * ODIM + (lq << 6);
            float* drow = resid + (bm + lrow) * ODIM + (lq << 6);
            float* qrow = qf + (bm + lrow) * ODIM + (lq << 6);
            #pragma unroll
            for (int j = 0; j < 16; ++j) {
                float4 s4 = *(const float4*)(srow + (j << 2));
                float4 c4 = *(const float4*)(crow + (j << 2));
                float4 r4;
                r4.x = s4.x - c4.x; r4.y = s4.y - c4.y; r4.z = s4.z - c4.z; r4.w = s4.w - c4.w;
                commit_local = fmaf(r4.x, r4.x, commit_local);
                commit_local = fmaf(r4.y, r4.y, commit_local);
                commit_local = fmaf(r4.z, r4.z, commit_local);
                commit_local = fmaf(r4.w, r4.w, commit_local);
                if (l < 3) *(float4*)(drow + (j << 2)) = r4;
                // q_final accumulated directly (decoder precision is uncritical)
                float4 q4;
                if (l == 0) { q4 = c4; }
                else {
                    float4 qo = *(const float4*)(qrow + (j << 2));
                    q4.x = qo.x + c4.x; q4.y = qo.y + c4.y; q4.z = qo.z + c4.z; q4.w = qo.w + c4.w;
                }
                *(float4*)(qrow + (j << 2)) = q4;
            }
        }
        __syncthreads();
    }
    if (t < 64) flag[bm + t] = flagreg;
    #pragma unroll
    for (int o = 32; o > 0; o >>= 1) commit_local += __shfl_xor(commit_local, o);
    if ((t & 63) == 0) cred[t >> 6] = commit_local;
    __syncthreads();
    if (t == 0) atomicAdd(acc_commit, (double)((cred[0] + cred[1]) + (cred[2] + cred[3])));
}

// f64 exact recompute of the index chain for flagged (near-tie) rows.
__global__ __launch_bounds__(256) void k_fix(
    const int* __restrict__ flag, const float* __restrict__ x,
    const float* __restrict__ lng, const float* __restrict__ lnb,
    const float* __restrict__ W1, const float* __restrict__ b1,
    const float* __restrict__ W2, const float* __restrict__ b2,
    const float* __restrict__ cb, float* __restrict__ oidx)
{
    const int row = blockIdx.x;
    if (!flag[row]) return;
    const int t = threadIdx.x;
    __shared__ double xn[INDIM];
    __shared__ double hs[ODIM];
    __shared__ double r[ODIM];
    __shared__ double rv_[4];
    __shared__ int ri_[4];
    __shared__ int selidx;

    const float* xr = x + (size_t)row * INDIM;
    double xa = (double)xr[t], xb = (double)xr[t + 256], xc = (double)xr[t + 512];
    double s1 = xa + xb + xc;
    double s2 = xa * xa + xb * xb + xc * xc;
    #pragma unroll
    for (int o = 32; o > 0; o >>= 1) { s1 += __shfl_xor(s1, o); s2 += __shfl_xor(s2, o); }
    __shared__ double w1r[4], w2r[4];
    if ((t & 63) == 0) { w1r[t >> 6] = s1; w2r[t >> 6] = s2; }
    __syncthreads();
    double S1 = (w1r[0] + w1r[1]) + (w1r[2] + w1r[3]);
    double S2 = (w2r[0] + w2r[1]) + (w2r[2] + w2r[3]);
    double mu = S1 / (double)INDIM;
    double var = S2 / (double)INDIM - mu * mu;
    double rs = 1.0 / sqrt(var + 1e-5);
    xn[t]       = (xa - mu) * rs * (double)lng[t]       + (double)lnb[t];
    xn[t + 256] = (xb - mu) * rs * (double)lng[t + 256] + (double)lnb[t + 256];
    xn[t + 512] = (xc - mu) * rs * (double)lng[t + 512] + (double)lnb[t + 512];
    __syncthreads();
    double h = (double)b1[t];
    for (int k = 0; k < INDIM; ++k) h += xn[k] * (double)W1[(size_t)k * ODIM + t];
    hs[t] = fmax(h, 0.0);
    __syncthreads();
    double e = (double)b2[t];
    for (int k = 0; k < ODIM; ++k) e += hs[k] * (double)W2[(size_t)k * ODIM + t];
    r[t] = e;
    __syncthreads();

    for (int l = 0; l < NLEV; ++l) {
        const float* cbl = cb + (size_t)l * CBS * ODIM;
        double bv = 1e300; int bi = 0;
        #pragma unroll
        for (int j = 0; j < 4; ++j) {
            const int code = t * 4 + j;
            const float* cr = cbl + (size_t)code * ODIM;
            double d = 0.0;
            for (int k = 0; k < ODIM; k += 4) {
                float4 c4 = *(const float4*)(cr + k);
                double d0 = r[k + 0] - (double)c4.x;
                double d1 = r[k + 1] - (double)c4.y;
                double d2 = r[k + 2] - (double)c4.z;
                double d3 = r[k + 3] - (double)c4.w;
                d += d0 * d0 + d1 * d1 + d2 * d2 + d3 * d3;
            }
            if (d < bv || (d == bv && code < bi)) { bv = d; bi = code; }
        }
        #pragma unroll
        for (int o = 32; o > 0; o >>= 1) {
            double ov = __shfl_xor(bv, o);
            int oi = __shfl_xor(bi, o);
            if (ov < bv || (ov == bv && oi < bi)) { bv = ov; bi = oi; }
        }
        if ((t & 63) == 0) { rv_[t >> 6] = bv; ri_[t >> 6] = bi; }
        __syncthreads();
        if (t == 0) {
            double fv = rv_[0]; int fi = ri_[0];
            #pragma unroll
            for (int w = 1; w < 4; ++w)
                if (rv_[w] < fv || (rv_[w] == fv && ri_[w] < fi)) { fv = rv_[w]; fi = ri_[w]; }
            selidx = fi;
            oidx[(size_t)row * NLEV + l] = (float)fi;
        }
        __syncthreads();
        r[t] = r[t] - (double)cb[(size_t)l * CBS * ODIM + (size_t)selidx * ODIM + t];
        __syncthreads();
    }
}

__global__ void k_fin(const double* __restrict__ acc, float* __restrict__ out) {
    if (threadIdx.x == 0)
        out[0] = (float)(acc[1] / ((double)NROWS * (double)INDIM) +
                         0.25 * (acc[0] / ((double)NROWS * (double)ODIM)));
}

extern "C" void kernel_launch(void* const* d_in, const int* in_sizes, int n_in,
                              void* d_out, int out_size, void* d_ws, size_t ws_size,
                              hipStream_t stream)
{
    const float* x   = (const float*)d_in[0];
    const float* lng = (const float*)d_in[1];
    const float* lnb = (const float*)d_in[2];
    const float* W1  = (const float*)d_in[3];
    const float* b1  = (const float*)d_in[4];
    const float* W2  = (const float*)d_in[5];
    const float* b2  = (const float*)d_in[6];
    const float* Wd1 = (const float*)d_in[7];
    const float* bd1 = (const float*)d_in[8];
    const float* Wd2 = (const float*)d_in[9];
    const float* bd2 = (const float*)d_in[10];
    const float* cbs = (const float*)d_in[11];

    char* ws = (char*)d_ws;
    const size_t O_ACC  = 0;
    const size_t O_CN   = 1024;
    const size_t O_MU   = O_CN + 16384;
    const size_t O_RS   = O_MU + (size_t)NROWS * 4;
    const size_t O_FLAG = O_RS + (size_t)NROWS * 4;
    const size_t O_ENC  = O_FLAG + (size_t)NROWS * 4;
    const size_t O_QF   = O_ENC + (size_t)NROWS * ODIM * 4;
    const size_t O_SCR  = O_QF + (size_t)NROWS * ODIM * 4;  // h1(f32) -> resid(f32) -> hd(bf16)

    double* acc   = (double*)(ws + O_ACC);   // [0]=commit sum, [1]=rec sum
    float* cnorm  = (float*)(ws + O_CN);
    float* mu     = (float*)(ws + O_MU);
    float* rsig   = (float*)(ws + O_RS);
    int*   flag   = (int*)(ws + O_FLAG);
    float* enc    = (float*)(ws + O_ENC);
    float* qf     = (float*)(ws + O_QF);
    float* h1     = (float*)(ws + O_SCR);
    float* resid  = (float*)(ws + O_SCR);
    unsigned short* hd = (unsigned short*)(ws + O_SCR);

    float* outF  = (float*)d_out;
    float* recon = outF + 1;
    float* oidx  = outF + 1 + (size_t)NROWS * INDIM;

    k_init<<<1, 64, 0, stream>>>(acc);
    k_cnorm<<<NLEV * CBS, 64, 0, stream>>>(cbs, cnorm);
    k_ln<<<NROWS, 256, 0, stream>>>(x, mu, rsig);
    // encoder
    k_gemm<1, 0><<<dim3(2, NROWS / 64), 256, 0, stream>>>(
        x, W1, b1, h1, INDIM, ODIM, mu, rsig, lng, lnb, nullptr, nullptr);
    k_gemm<0, 1><<<dim3(2, NROWS / 64), 256, 0, stream>>>(
        h1, W2, b2, enc, ODIM, ODIM, nullptr, nullptr, nullptr, nullptr, nullptr, nullptr);
    // residual quantization (4 levels fused) + near-tie flags
    k_quant<<<NROWS / 64, 256, 0, stream>>>(enc, cbs, cnorm, resid, qf, oidx, flag, acc);
    // f64 exact index fix for flagged rows
    k_fix<<<NROWS, 256, 0, stream>>>(flag, x, lng, lnb, W1, b1, W2, b2, cbs, oidx);
    // decoder
    k_gemm<0, 2><<<dim3(6, NROWS / 64), 256, 0, stream>>>(
        qf, Wd1, bd1, hd, ODIM, INDIM, nullptr, nullptr, nullptr, nullptr, nullptr, nullptr);
    k_gemm<2, 3><<<dim3(6, NROWS / 64), 256, 0, stream>>>(
        hd, Wd2, bd2, recon, INDIM, INDIM, nullptr, nullptr, nullptr, nullptr, x, acc + 1);
    k_fin<<<1, 64, 0, stream>>>(acc, outF);
}

// Round 2
// 3105.653 us; speedup vs baseline: 1.4447x; 1.4447x over previous
//
#include <hip/hip_runtime.h>
#include <hip/hip_bf16.h>
#include <stdint.h>

#define NROWS 65536
#define INDIM 768
#define ODIM  256
#define NLEV  4
#define CBS   1024
#define TAUQ  2e-2f   // top-2 gap threshold for f64 re-check (split-MFMA error ~3e-4, ~60x margin)

typedef __attribute__((ext_vector_type(8))) short short8;
typedef __attribute__((ext_vector_type(4))) float f32x4;

__device__ __forceinline__ float bf2f(unsigned short u) {
    union { unsigned int i; float f; } v; v.i = ((unsigned int)u) << 16; return v.f;
}
__device__ __forceinline__ unsigned short f2bf(float f) {
    union { float f; unsigned int i; } v; v.f = f;
    unsigned int r = v.i + 0x7fffu + ((v.i >> 16) & 1u);
    return (unsigned short)(r >> 16);
}
__device__ __forceinline__ f32x4 mfma_bf16(short8 a, short8 b, f32x4 c) {
    return __builtin_amdgcn_mfma_f32_16x16x32_bf16(a, b, c, 0, 0, 0);
}

__global__ void k_init(double* __restrict__ acc) {
    if (threadIdx.x < 2) acc[threadIdx.x] = 0.0;
}

// ||c||^2 per codebook row
__global__ __launch_bounds__(64) void k_cnorm(const float* __restrict__ cb, float* __restrict__ cn) {
    const int code = blockIdx.x;
    const float* r = cb + (size_t)code * ODIM + threadIdx.x * 4;
    float4 v = *(const float4*)r;
    float s = fmaf(v.x, v.x, fmaf(v.y, v.y, fmaf(v.z, v.z, v.w * v.w)));
    #pragma unroll
    for (int o = 32; o > 0; o >>= 1) s += __shfl_xor(s, o);
    if (threadIdx.x == 0) cn[code] = s;
}

// split codebooks into hi/lo bf16
__global__ __launch_bounds__(256) void k_split(const float* __restrict__ cb,
                                               unsigned short* __restrict__ ch,
                                               unsigned short* __restrict__ cl) {
    const size_t i = ((size_t)blockIdx.x * 256 + threadIdx.x) * 4;
    float4 v = *(const float4*)(cb + i);
    float e[4] = {v.x, v.y, v.z, v.w};
    ushort4 h, l;
    unsigned short* hp = &h.x; unsigned short* lp = &l.x;
    #pragma unroll
    for (int j = 0; j < 4; ++j) {
        unsigned short hh = f2bf(e[j]);
        hp[j] = hh;
        lp[j] = f2bf(e[j] - bf2f(hh));
    }
    *(ushort4*)(ch + i) = h;
    *(ushort4*)(cl + i) = l;
}

// per-row mean / rsqrt(var+eps)
__global__ __launch_bounds__(256) void k_ln(const float* __restrict__ x,
                                            float* __restrict__ mu, float* __restrict__ rsig) {
    const int row = blockIdx.x;
    const int t = threadIdx.x;
    const float* xr = x + (size_t)row * INDIM;
    float a = xr[t], b = xr[t + 256], c = xr[t + 512];
    float s1 = a + b + c;
    float s2 = fmaf(a, a, fmaf(b, b, c * c));
    #pragma unroll
    for (int o = 32; o > 0; o >>= 1) { s1 += __shfl_xor(s1, o); s2 += __shfl_xor(s2, o); }
    __shared__ float r1[4], r2[4];
    if ((t & 63) == 0) { r1[t >> 6] = s1; r2[t >> 6] = s2; }
    __syncthreads();
    if (t == 0) {
        float S1 = (r1[0] + r1[1]) + (r1[2] + r1[3]);
        float S2 = (r2[0] + r2[1]) + (r2[2] + r2[3]);
        float m = S1 * (1.0f / INDIM);
        float var = S2 * (1.0f / INDIM) - m * m;
        mu[row] = m;
        rsig[row] = rsqrtf(var + 1e-5f);
    }
}

// C[M,Nc] = op(A[M,K]) @ B[K,Nc] + bias.  Tiles: 64(M) x 128(N) x 16(K), 256 thr, 4x8 acc.
// AMODE: 0 plain f32 A, 1 LayerNorm-on-load (A=x), 2 bf16 A
// EPI:   0 relu->f32, 1 f32, 2 relu->bf16, 3 f32 + sum((C-xref)^2) into acc_rec
template <int AMODE, int EPI>
__global__ __launch_bounds__(256) void k_gemm(
    const void* __restrict__ Ap, const float* __restrict__ B,
    const float* __restrict__ bias, void* __restrict__ Cp,
    const int K, const int Nc,
    const float* __restrict__ mu, const float* __restrict__ rsig,
    const float* __restrict__ lng, const float* __restrict__ lnb,
    const float* __restrict__ xref, double* __restrict__ acc_rec)
{
    __shared__ float At[16 * 64];    // [k][m]
    __shared__ float Bt[16 * 128];   // [k][n]
    __shared__ float red[4];
    float acc[4][8];
    #pragma unroll
    for (int i = 0; i < 4; ++i)
        #pragma unroll
        for (int j = 0; j < 8; ++j) acc[i][j] = 0.0f;

    const int t = threadIdx.x;
    const int tx = t & 15, ty = t >> 4;
    const size_t bm = (size_t)blockIdx.y * 64;
    const int bn = blockIdx.x * 128;
    const int lm = t >> 2, lk = (t & 3) << 2;
    const int bk = t >> 4, bnn = (t & 15) << 3;
    float lnm = 0.f, lnr = 0.f;
    if (AMODE == 1) { lnm = mu[bm + lm]; lnr = rsig[bm + lm]; }

    for (int kk = 0; kk < K; kk += 16) {
        float4 av;
        if (AMODE == 0) {
            av = *(const float4*)((const float*)Ap + (bm + lm) * (size_t)K + kk + lk);
        } else if (AMODE == 1) {
            float4 xv = *(const float4*)((const float*)Ap + (bm + lm) * (size_t)K + kk + lk);
            float4 g  = *(const float4*)(lng + kk + lk);
            float4 bb = *(const float4*)(lnb + kk + lk);
            av.x = fmaf((xv.x - lnm) * lnr, g.x, bb.x);
            av.y = fmaf((xv.y - lnm) * lnr, g.y, bb.y);
            av.z = fmaf((xv.z - lnm) * lnr, g.z, bb.z);
            av.w = fmaf((xv.w - lnm) * lnr, g.w, bb.w);
        } else {
            ushort4 uv = *(const ushort4*)((const unsigned short*)Ap + (bm + lm) * (size_t)K + kk + lk);
            av.x = bf2f(uv.x); av.y = bf2f(uv.y); av.z = bf2f(uv.z); av.w = bf2f(uv.w);
        }
        float4 bv0 = *(const float4*)(B + (size_t)(kk + bk) * Nc + bn + bnn);
        float4 bv1 = *(const float4*)(B + (size_t)(kk + bk) * Nc + bn + bnn + 4);
        __syncthreads();
        At[(lk + 0) * 64 + lm] = av.x;
        At[(lk + 1) * 64 + lm] = av.y;
        At[(lk + 2) * 64 + lm] = av.z;
        At[(lk + 3) * 64 + lm] = av.w;
        *(float4*)&Bt[bk * 128 + bnn] = bv0;
        *(float4*)&Bt[bk * 128 + bnn + 4] = bv1;
        __syncthreads();
        #pragma unroll
        for (int k = 0; k < 16; ++k) {
            float a[4], b[8];
            *(float4*)a = *(float4*)&At[k * 64 + (ty << 2)];
            *(float4*)&b[0] = *(float4*)&Bt[k * 128 + (tx << 2)];
            *(float4*)&b[4] = *(float4*)&Bt[k * 128 + 64 + (tx << 2)];
            #pragma unroll
            for (int i = 0; i < 4; ++i)
                #pragma unroll
                for (int j = 0; j < 8; ++j)
                    acc[i][j] = fmaf(a[i], b[j], acc[i][j]);
        }
    }

    const int col0 = bn + (tx << 2);
    float4 bs0 = *(const float4*)(bias + col0);
    float4 bs1 = *(const float4*)(bias + col0 + 64);
    float lsum = 0.0f;
    #pragma unroll
    for (int i = 0; i < 4; ++i) {
        const size_t row = bm + (ty << 2) + i;
        float v[8];
        v[0] = acc[i][0] + bs0.x; v[1] = acc[i][1] + bs0.y;
        v[2] = acc[i][2] + bs0.z; v[3] = acc[i][3] + bs0.w;
        v[4] = acc[i][4] + bs1.x; v[5] = acc[i][5] + bs1.y;
        v[6] = acc[i][6] + bs1.z; v[7] = acc[i][7] + bs1.w;
        if (EPI == 0 || EPI == 2) {
            #pragma unroll
            for (int j = 0; j < 8; ++j) v[j] = fmaxf(v[j], 0.0f);
        }
        if (EPI == 2) {
            unsigned short* crow = (unsigned short*)Cp + row * Nc + col0;
            *(ushort4*)crow        = make_ushort4(f2bf(v[0]), f2bf(v[1]), f2bf(v[2]), f2bf(v[3]));
            *(ushort4*)(crow + 64) = make_ushort4(f2bf(v[4]), f2bf(v[5]), f2bf(v[6]), f2bf(v[7]));
        } else {
            float* crow = (float*)Cp + row * Nc + col0;
            *(float4*)crow        = make_float4(v[0], v[1], v[2], v[3]);
            *(float4*)(crow + 64) = make_float4(v[4], v[5], v[6], v[7]);
        }
        if (EPI == 3) {
            const float* xr = xref + row * INDIM + col0;
            float4 x0 = *(const float4*)xr;
            float4 x1 = *(const float4*)(xr + 64);
            float d;
            d = v[0] - x0.x; lsum = fmaf(d, d, lsum);
            d = v[1] - x0.y; lsum = fmaf(d, d, lsum);
            d = v[2] - x0.z; lsum = fmaf(d, d, lsum);
            d = v[3] - x0.w; lsum = fmaf(d, d, lsum);
            d = v[4] - x1.x; lsum = fmaf(d, d, lsum);
            d = v[5] - x1.y; lsum = fmaf(d, d, lsum);
            d = v[6] - x1.z; lsum = fmaf(d, d, lsum);
            d = v[7] - x1.w; lsum = fmaf(d, d, lsum);
        }
    }
    if (EPI == 3) {
        #pragma unroll
        for (int o = 32; o > 0; o >>= 1) lsum += __shfl_xor(lsum, o);
        if ((t & 63) == 0) red[t >> 6] = lsum;
        __syncthreads();
        if (t == 0) atomicAdd(acc_rec, (double)((red[0] + red[1]) + (red[2] + red[3])));
    }
}

// Fused 4-level residual quantization, MFMA bf16x2-split edition.
// Block = 256 thr = 4 waves; wave owns 32 rows (2 MFMA m-tiles) held entirely in
// registers as hi/lo bf16 A-fragments. Codebook hi/lo streamed through LDS in
// 32-code chunks. dist = ||c||^2 - 2*(r_hi.c_hi + r_lo.c_hi + r_hi.c_lo).
__global__ __launch_bounds__(256, 2) void k_quant_mfma(
    const float* __restrict__ enc, const float* __restrict__ cb,
    const unsigned short* __restrict__ cbh, const unsigned short* __restrict__ cbl,
    const float* __restrict__ cnorm, float* __restrict__ qf, float* __restrict__ oidx,
    int* __restrict__ flag, double* __restrict__ acc_commit)
{
    __shared__ unsigned short Bh[32][264];   // 32 codes x 256 k, pad 8 (2-way-free b128 reads)
    __shared__ unsigned short Bl[32][264];
    __shared__ __align__(16) int rowidxsh[128];
    __shared__ float credsh[4];

    const int t = threadIdx.x;
    const int wave = t >> 6, lane = t & 63;
    const int lg = lane >> 4, lm = lane & 15;
    const size_t rowbase = (size_t)blockIdx.x * 128 + wave * 32;

    // ---- load enc rows into hi/lo A-fragments (A[m=lane&15][k=lg*8+j], 8 k-steps) ----
    short8 Ah[2][8], Al[2][8];
    #pragma unroll
    for (int mt = 0; mt < 2; ++mt)
        #pragma unroll
        for (int s = 0; s < 8; ++s) {
            const float* er = enc + (rowbase + mt * 16 + lm) * ODIM + s * 32 + lg * 8;
            float4 e0 = *(const float4*)er;
            float4 e1 = *(const float4*)(er + 4);
            float e[8] = {e0.x, e0.y, e0.z, e0.w, e1.x, e1.y, e1.z, e1.w};
            #pragma unroll
            for (int j = 0; j < 8; ++j) {
                unsigned short h = f2bf(e[j]);
                Ah[mt][s][j] = (short)h;
                Al[mt][s][j] = (short)f2bf(e[j] - bf2f(h));
            }
        }

    float commit_local = 0.0f;
    int flg[2][4] = {{0, 0, 0, 0}, {0, 0, 0, 0}};

    for (int l = 0; l < NLEV; ++l) {
        const size_t lbase = (size_t)l * CBS * ODIM;
        float bestv[2][4], b2v[2][4];
        int besti[2][4];
        #pragma unroll
        for (int mt = 0; mt < 2; ++mt)
            #pragma unroll
            for (int r = 0; r < 4; ++r) { bestv[mt][r] = 3.4e38f; b2v[mt][r] = 3.4e38f; besti[mt][r] = 0; }

        for (int ch = 0; ch < 32; ++ch) {
            const int cbase = ch << 5;
            __syncthreads();
            // stage 32 codes of hi/lo codebook into LDS (coalesced 16B, padded rows)
            {
                const unsigned short* gh = cbh + lbase + (size_t)cbase * ODIM;
                const unsigned short* gl = cbl + lbase + (size_t)cbase * ODIM;
                #pragma unroll
                for (int r = 0; r < 4; ++r) {
                    const int i = (r << 8) + t;           // 0..1023 slots of 8 shorts
                    const int code = i >> 5, sl = i & 31;
                    *(uint4*)&Bh[code][sl << 3] = *(const uint4*)(gh + ((size_t)i << 3));
                    *(uint4*)&Bl[code][sl << 3] = *(const uint4*)(gl + ((size_t)i << 3));
                }
            }
            __syncthreads();
            #pragma unroll
            for (int nt = 0; nt < 2; ++nt) {
                f32x4 hh[2], lh[2], hl[2];
                #pragma unroll
                for (int mt = 0; mt < 2; ++mt) {
                    hh[mt] = (f32x4){0.f, 0.f, 0.f, 0.f};
                    lh[mt] = (f32x4){0.f, 0.f, 0.f, 0.f};
                    hl[mt] = (f32x4){0.f, 0.f, 0.f, 0.f};
                }
                #pragma unroll
                for (int s = 0; s < 8; ++s) {
                    short8 bh = *(const short8*)&Bh[(nt << 4) + lm][(s << 5) + (lg << 3)];
                    short8 bl = *(const short8*)&Bl[(nt << 4) + lm][(s << 5) + (lg << 3)];
                    hh[0] = mfma_bf16(Ah[0][s], bh, hh[0]);
                    hh[1] = mfma_bf16(Ah[1][s], bh, hh[1]);
                    lh[0] = mfma_bf16(Al[0][s], bh, lh[0]);
                    lh[1] = mfma_bf16(Al[1][s], bh, lh[1]);
                    hl[0] = mfma_bf16(Ah[0][s], bl, hl[0]);
                    hl[1] = mfma_bf16(Ah[1][s], bl, hl[1]);
                }
                const int code = cbase + (nt << 4) + lm;
                const float cn = cnorm[(l << 10) + code];
                #pragma unroll
                for (int mt = 0; mt < 2; ++mt)
                    #pragma unroll
                    for (int r = 0; r < 4; ++r) {
                        const float dot = hh[mt][r] + lh[mt][r] + hl[mt][r];
                        const float d = fmaf(-2.0f, dot, cn);
                        if (d < bestv[mt][r]) {
                            b2v[mt][r] = bestv[mt][r]; bestv[mt][r] = d; besti[mt][r] = code;
                        } else {
                            b2v[mt][r] = fminf(b2v[mt][r], d);
                        }
                    }
            }
        }

        // ---- cross-lane argmin over the 16 C-columns (xor butterfly in low 4 lane bits) ----
        #pragma unroll
        for (int mt = 0; mt < 2; ++mt) {
            int iv[4];
            #pragma unroll
            for (int r = 0; r < 4; ++r) {
                float bv = bestv[mt][r], b2 = b2v[mt][r];
                int bi = besti[mt][r];
                #pragma unroll
                for (int off = 1; off < 16; off <<= 1) {
                    float ov = __shfl_xor(bv, off);
                    float o2 = __shfl_xor(b2, off);
                    int   oi = __shfl_xor(bi, off);
                    if (ov < bv)      { b2 = fminf(bv, o2); bv = ov; bi = oi; }
                    else if (ov > bv) { b2 = fminf(b2, ov); }
                    else              { b2 = bv; bi = (oi < bi) ? oi : bi; }
                }
                flg[mt][r] |= (b2 - bv < TAUQ) ? 1 : 0;
                iv[r] = bi;
                if (lm == 0)
                    oidx[(rowbase + (mt << 4) + (lg << 2) + r) * NLEV + l] = (float)bi;
            }
            if (lm == 0)
                *(int4*)&rowidxsh[(wave << 5) + (mt << 4) + (lg << 2)] = make_int4(iv[0], iv[1], iv[2], iv[3]);
        }
        __syncthreads();

        // ---- residual update in registers: r -= cb[best]; commit += r^2; re-split ----
        #pragma unroll
        for (int mt = 0; mt < 2; ++mt) {
            const int ci = rowidxsh[(wave << 5) + (mt << 4) + lm];
            const float* cr = cb + lbase + (size_t)ci * ODIM + lg * 8;
            #pragma unroll
            for (int s = 0; s < 8; ++s) {
                float4 c0 = *(const float4*)(cr + (s << 5));
                float4 c1 = *(const float4*)(cr + (s << 5) + 4);
                float c[8] = {c0.x, c0.y, c0.z, c0.w, c1.x, c1.y, c1.z, c1.w};
                #pragma unroll
                for (int j = 0; j < 8; ++j) {
                    float rr = bf2f((unsigned short)Ah[mt][s][j]) + bf2f((unsigned short)Al[mt][s][j]) - c[j];
                    commit_local = fmaf(rr, rr, commit_local);
                    unsigned short h = f2bf(rr);
                    Ah[mt][s][j] = (short)h;
                    Al[mt][s][j] = (short)f2bf(rr - bf2f(h));
                }
            }
        }
    }

    // ---- q_final = enc - r_final ----
    #pragma unroll
    for (int mt = 0; mt < 2; ++mt)
        #pragma unroll
        for (int s = 0; s < 8; ++s) {
            const size_t ro = (rowbase + mt * 16 + lm) * ODIM + s * 32 + lg * 8;
            float4 e0 = *(const float4*)(enc + ro);
            float4 e1 = *(const float4*)(enc + ro + 4);
            float e[8] = {e0.x, e0.y, e0.z, e0.w, e1.x, e1.y, e1.z, e1.w};
            float q[8];
            #pragma unroll
            for (int j = 0; j < 8; ++j)
                q[j] = e[j] - (bf2f((unsigned short)Ah[mt][s][j]) + bf2f((unsigned short)Al[mt][s][j]));
            *(float4*)(qf + ro)     = make_float4(q[0], q[1], q[2], q[3]);
            *(float4*)(qf + ro + 4) = make_float4(q[4], q[5], q[6], q[7]);
        }

    if (lm == 0) {
        #pragma unroll
        for (int mt = 0; mt < 2; ++mt)
            #pragma unroll
            for (int r = 0; r < 4; ++r)
                flag[rowbase + (mt << 4) + (lg << 2) + r] = flg[mt][r];
    }

    #pragma unroll
    for (int o = 32; o > 0; o >>= 1) commit_local += __shfl_xor(commit_local, o);
    if (lane == 0) credsh[wave] = commit_local;
    __syncthreads();
    if (t == 0) atomicAdd(acc_commit, (double)((credsh[0] + credsh[1]) + (credsh[2] + credsh[3])));
}

// f64 exact recompute of the index chain for flagged (near-tie) rows.
__global__ __launch_bounds__(256) void k_fix(
    const int* __restrict__ flag, const float* __restrict__ x,
    const float* __restrict__ lng, const float* __restrict__ lnb,
    const float* __restrict__ W1, const float* __restrict__ b1,
    const float* __restrict__ W2, const float* __restrict__ b2,
    const float* __restrict__ cb, float* __restrict__ oidx)
{
    const int row = blockIdx.x;
    if (!flag[row]) return;
    const int t = threadIdx.x;
    __shared__ double xn[INDIM];
    __shared__ double hs[ODIM];
    __shared__ double r[ODIM];
    __shared__ double rv_[4];
    __shared__ int ri_[4];
    __shared__ int selidx;

    const float* xr = x + (size_t)row * INDIM;
    double xa = (double)xr[t], xb = (double)xr[t + 256], xc = (double)xr[t + 512];
    double s1 = xa + xb + xc;
    double s2 = xa * xa + xb * xb + xc * xc;
    #pragma unroll
    for (int o = 32; o > 0; o >>= 1) { s1 += __shfl_xor(s1, o); s2 += __shfl_xor(s2, o); }
    __shared__ double w1r[4], w2r[4];
    if ((t & 63) == 0) { w1r[t >> 6] = s1; w2r[t >> 6] = s2; }
    __syncthreads();
    double S1 = (w1r[0] + w1r[1]) + (w1r[2] + w1r[3]);
    double S2 = (w2r[0] + w2r[1]) + (w2r[2] + w2r[3]);
    double mu = S1 / (double)INDIM;
    double var = S2 / (double)INDIM - mu * mu;
    double rs = 1.0 / sqrt(var + 1e-5);
    xn[t]       = (xa - mu) * rs * (double)lng[t]       + (double)lnb[t];
    xn[t + 256] = (xb - mu) * rs * (double)lng[t + 256] + (double)lnb[t + 256];
    xn[t + 512] = (xc - mu) * rs * (double)lng[t + 512] + (double)lnb[t + 512];
    __syncthreads();
    double h = (double)b1[t];
    for (int k = 0; k < INDIM; ++k) h += xn[k] * (double)W1[(size_t)k * ODIM + t];
    hs[t] = fmax(h, 0.0);
    __syncthreads();
    double e = (double)b2[t];
    for (int k = 0; k < ODIM; ++k) e += hs[k] * (double)W2[(size_t)k * ODIM + t];
    r[t] = e;
    __syncthreads();

    for (int l = 0; l < NLEV; ++l) {
        const float* cbl = cb + (size_t)l * CBS * ODIM;
        double bv = 1e300; int bi = 0;
        #pragma unroll
        for (int j = 0; j < 4; ++j) {
            const int code = t * 4 + j;
            const float* cr = cbl + (size_t)code * ODIM;
            double d = 0.0;
            for (int k = 0; k < ODIM; k += 4) {
                float4 c4 = *(const float4*)(cr + k);
                double d0 = r[k + 0] - (double)c4.x;
                double d1 = r[k + 1] - (double)c4.y;
                double d2 = r[k + 2] - (double)c4.z;
                double d3 = r[k + 3] - (double)c4.w;
                d += d0 * d0 + d1 * d1 + d2 * d2 + d3 * d3;
            }
            if (d < bv || (d == bv && code < bi)) { bv = d; bi = code; }
        }
        #pragma unroll
        for (int o = 32; o > 0; o >>= 1) {
            double ov = __shfl_xor(bv, o);
            int oi = __shfl_xor(bi, o);
            if (ov < bv || (ov == bv && oi < bi)) { bv = ov; bi = oi; }
        }
        if ((t & 63) == 0) { rv_[t >> 6] = bv; ri_[t >> 6] = bi; }
        __syncthreads();
        if (t == 0) {
            double fv = rv_[0]; int fi = ri_[0];
            #pragma unroll
            for (int w = 1; w < 4; ++w)
                if (rv_[w] < fv || (rv_[w] == fv && ri_[w] < fi)) { fv = rv_[w]; fi = ri_[w]; }
            selidx = fi;
            oidx[(size_t)row * NLEV + l] = (float)fi;
        }
        __syncthreads();
        r[t] = r[t] - (double)cb[(size_t)l * CBS * ODIM + (size_t)selidx * ODIM + t];
        __syncthreads();
    }
}

__global__ void k_fin(const double* __restrict__ acc, float* __restrict__ out) {
    if (threadIdx.x == 0)
        out[0] = (float)(acc[1] / ((double)NROWS * (double)INDIM) +
                         0.25 * (acc[0] / ((double)NROWS * (double)ODIM)));
}

extern "C" void kernel_launch(void* const* d_in, const int* in_sizes, int n_in,
                              void* d_out, int out_size, void* d_ws, size_t ws_size,
                              hipStream_t stream)
{
    const float* x   = (const float*)d_in[0];
    const float* lng = (const float*)d_in[1];
    const float* lnb = (const float*)d_in[2];
    const float* W1  = (const float*)d_in[3];
    const float* b1  = (const float*)d_in[4];
    const float* W2  = (const float*)d_in[5];
    const float* b2  = (const float*)d_in[6];
    const float* Wd1 = (const float*)d_in[7];
    const float* bd1 = (const float*)d_in[8];
    const float* Wd2 = (const float*)d_in[9];
    const float* bd2 = (const float*)d_in[10];
    const float* cbs = (const float*)d_in[11];

    char* ws = (char*)d_ws;
    const size_t O_ACC  = 0;
    const size_t O_CN   = 1024;
    const size_t O_MU   = O_CN + 16384;
    const size_t O_RS   = O_MU + (size_t)NROWS * 4;
    const size_t O_FLAG = O_RS + (size_t)NROWS * 4;
    const size_t O_ENC  = O_FLAG + (size_t)NROWS * 4;
    const size_t O_QF   = O_ENC + (size_t)NROWS * ODIM * 4;
    const size_t O_SCR  = O_QF + (size_t)NROWS * ODIM * 4;  // h1(f32) -> cbh/cbl(bf16) -> hd(bf16)

    double* acc   = (double*)(ws + O_ACC);   // [0]=commit sum, [1]=rec sum
    float* cnorm  = (float*)(ws + O_CN);
    float* mu     = (float*)(ws + O_MU);
    float* rsig   = (float*)(ws + O_RS);
    int*   flag   = (int*)(ws + O_FLAG);
    float* enc    = (float*)(ws + O_ENC);
    float* qf     = (float*)(ws + O_QF);
    float* h1     = (float*)(ws + O_SCR);
    unsigned short* cbh = (unsigned short*)(ws + O_SCR);                        // 2 MB
    unsigned short* cbl = (unsigned short*)(ws + O_SCR + (size_t)NLEV * CBS * ODIM * 2);
    unsigned short* hd  = (unsigned short*)(ws + O_SCR);

    float* outF  = (float*)d_out;
    float* recon = outF + 1;
    float* oidx  = outF + 1 + (size_t)NROWS * INDIM;

    k_init<<<1, 64, 0, stream>>>(acc);
    k_cnorm<<<NLEV * CBS, 64, 0, stream>>>(cbs, cnorm);
    k_ln<<<NROWS, 256, 0, stream>>>(x, mu, rsig);
    // encoder (h1 occupies O_SCR until gemm2 consumes it)
    k_gemm<1, 0><<<dim3(2, NROWS / 64), 256, 0, stream>>>(
        x, W1, b1, h1, INDIM, ODIM, mu, rsig, lng, lnb, nullptr, nullptr);
    k_gemm<0, 1><<<dim3(2, NROWS / 64), 256, 0, stream>>>(
        h1, W2, b2, enc, ODIM, ODIM, nullptr, nullptr, nullptr, nullptr, nullptr, nullptr);
    // codebook hi/lo split (reuses O_SCR, h1 now dead)
    k_split<<<(NLEV * CBS * ODIM) / 1024, 256, 0, stream>>>(cbs, cbh, cbl);
    // residual quantization: MFMA bf16x2-split + near-tie flags
    k_quant_mfma<<<NROWS / 128, 256, 0, stream>>>(enc, cbs, cbh, cbl, cnorm, qf, oidx, flag, acc);
    // f64 exact index fix for flagged rows
    k_fix<<<NROWS, 256, 0, stream>>>(flag, x, lng, lnb, W1, b1, W2, b2, cbs, oidx);
    // decoder (hd overwrites cbh/cbl region, quant is done)
    k_gemm<0, 2><<<dim3(6, NROWS / 64), 256, 0, stream>>>(
        qf, Wd1, bd1, hd, ODIM, INDIM, nullptr, nullptr, nullptr, nullptr, nullptr, nullptr);
    k_gemm<2, 3><<<dim3(6, NROWS / 64), 256, 0, stream>>>(
        hd, Wd2, bd2, recon, INDIM, INDIM, nullptr, nullptr, nullptr, nullptr, x, acc + 1);
    k_fin<<<1, 64, 0, stream>>>(acc, outF);
}

// Round 3
// 2096.118 us; speedup vs baseline: 2.1405x; 1.4816x over previous
//
#include <hip/hip_runtime.h>
#include <hip/hip_bf16.h>
#include <stdint.h>

#define NROWS 65536
#define INDIM 768
#define ODIM  256
#define NLEV  4
#define CBS   1024
#define TAUQ  2e-2f   // top-2 gap threshold for f64 re-check (split-MFMA error ~1e-3 worst, ~20x margin)

typedef __attribute__((ext_vector_type(8))) short short8;
typedef __attribute__((ext_vector_type(4))) float f32x4;

__device__ __forceinline__ float bf2f(unsigned short u) {
    union { unsigned int i; float f; } v; v.i = ((unsigned int)u) << 16; return v.f;
}
__device__ __forceinline__ unsigned short f2bf(float f) {
    union { float f; unsigned int i; } v; v.f = f;
    unsigned int r = v.i + 0x7fffu + ((v.i >> 16) & 1u);
    return (unsigned short)(r >> 16);
}
__device__ __forceinline__ f32x4 mfma_bf16(short8 a, short8 b, f32x4 c) {
    return __builtin_amdgcn_mfma_f32_16x16x32_bf16(a, b, c, 0, 0, 0);
}

__global__ void k_init(double* __restrict__ acc) {
    if (threadIdx.x < 2) acc[threadIdx.x] = 0.0;
}

// ||c||^2 per codebook row
__global__ __launch_bounds__(64) void k_cnorm(const float* __restrict__ cb, float* __restrict__ cn) {
    const int code = blockIdx.x;
    const float* r = cb + (size_t)code * ODIM + threadIdx.x * 4;
    float4 v = *(const float4*)r;
    float s = fmaf(v.x, v.x, fmaf(v.y, v.y, fmaf(v.z, v.z, v.w * v.w)));
    #pragma unroll
    for (int o = 32; o > 0; o >>= 1) s += __shfl_xor(s, o);
    if (threadIdx.x == 0) cn[code] = s;
}

// split codebooks into hi/lo bf16
__global__ __launch_bounds__(256) void k_split(const float* __restrict__ cb,
                                               unsigned short* __restrict__ ch,
                                               unsigned short* __restrict__ cl) {
    const size_t i = ((size_t)blockIdx.x * 256 + threadIdx.x) * 4;
    float4 v = *(const float4*)(cb + i);
    float e[4] = {v.x, v.y, v.z, v.w};
    ushort4 h, l;
    unsigned short* hp = &h.x; unsigned short* lp = &l.x;
    #pragma unroll
    for (int j = 0; j < 4; ++j) {
        unsigned short hh = f2bf(e[j]);
        hp[j] = hh;
        lp[j] = f2bf(e[j] - bf2f(hh));
    }
    *(ushort4*)(ch + i) = h;
    *(ushort4*)(cl + i) = l;
}

// transpose weight W[K][N] -> Th/Tl[N][K] bf16 (hi / optional lo)
__global__ __launch_bounds__(256) void k_wt(const float* __restrict__ W,
                                            unsigned short* __restrict__ Th,
                                            unsigned short* __restrict__ Tl,
                                            const int K, const int N, const int split) {
    const int n = blockIdx.x;
    for (int k = threadIdx.x; k < K; k += 256) {
        float v = W[(size_t)k * N + n];
        unsigned short h = f2bf(v);
        Th[(size_t)n * K + k] = h;
        if (split) Tl[(size_t)n * K + k] = f2bf(v - bf2f(h));
    }
}

// per-row mean / rsqrt(var+eps)
__global__ __launch_bounds__(256) void k_ln(const float* __restrict__ x,
                                            float* __restrict__ mu, float* __restrict__ rsig) {
    const int row = blockIdx.x;
    const int t = threadIdx.x;
    const float* xr = x + (size_t)row * INDIM;
    float a = xr[t], b = xr[t + 256], c = xr[t + 512];
    float s1 = a + b + c;
    float s2 = fmaf(a, a, fmaf(b, b, c * c));
    #pragma unroll
    for (int o = 32; o > 0; o >>= 1) { s1 += __shfl_xor(s1, o); s2 += __shfl_xor(s2, o); }
    __shared__ float r1[4], r2[4];
    if ((t & 63) == 0) { r1[t >> 6] = s1; r2[t >> 6] = s2; }
    __syncthreads();
    if (t == 0) {
        float S1 = (r1[0] + r1[1]) + (r1[2] + r1[3]);
        float S2 = (r2[0] + r2[1]) + (r2[2] + r2[3]);
        float m = S1 * (1.0f / INDIM);
        float var = S2 * (1.0f / INDIM) - m * m;
        mu[row] = m;
        rsig[row] = rsqrtf(var + 1e-5f);
    }
}

// MFMA GEMM: C[M,Nc] = op(A[M,K]) @ Bt^T + bias, Bt pre-transposed [Nc][K] bf16.
// Block: 128(M) x 256(N), 4 waves in 2x2; wave tile 64m x 128n = 4mt x 8nt (acc 128 f32/lane).
// AMODE: 0 f32 A (split hi/lo), 1 LayerNorm-on-load f32 A (split), 2 bf16 A (plain)
// SPLIT: 1 = bf16x2-split (3 MFMAs: hh + lh + hl), 0 = plain bf16
// EPI:   0 relu->f32, 1 f32, 2 relu->bf16, 3 f32 + sum((C-xref)^2) into acc_rec
template <int AMODE, int SPLIT, int EPI>
__global__ __launch_bounds__(256, 2) void k_gemm_mfma(
    const void* __restrict__ Ap, const unsigned short* __restrict__ Bh,
    const unsigned short* __restrict__ Bl,
    const float* __restrict__ bias, void* __restrict__ Cp,
    const int K, const int Nc,
    const float* __restrict__ mu, const float* __restrict__ rsig,
    const float* __restrict__ lng, const float* __restrict__ lnb,
    const float* __restrict__ xref, double* __restrict__ acc_rec)
{
    __shared__ __align__(16) unsigned short BhS[256][40];             // [n][k] pad 8
    __shared__ __align__(16) unsigned short BlS[SPLIT ? 256 : 8][SPLIT ? 40 : 8];
    __shared__ float credsh[4];

    const int t = threadIdx.x;
    const int wave = t >> 6, lane = t & 63;
    const int lg = lane >> 4, lm = lane & 15;
    const int wm = wave >> 1, wn = wave & 1;
    const size_t rowb = (size_t)blockIdx.y * 128 + wm * 64;
    const int nb = blockIdx.x << 8;

    f32x4 acc[4][8];
    #pragma unroll
    for (int mt = 0; mt < 4; ++mt)
        #pragma unroll
        for (int nt = 0; nt < 8; ++nt) acc[mt][nt] = (f32x4){0.f, 0.f, 0.f, 0.f};

    float lnm[4], lnr[4];
    if (AMODE == 1) {
        #pragma unroll
        for (int mt = 0; mt < 4; ++mt) {
            lnm[mt] = mu[rowb + (mt << 4) + lm];
            lnr[mt] = rsig[rowb + (mt << 4) + lm];
        }
    }

    for (int kk = 0; kk < K; kk += 32) {
        // ---- A fragments: per-lane direct global loads ----
        short8 Ah[4], Al[4];
        if (AMODE == 2) {
            #pragma unroll
            for (int mt = 0; mt < 4; ++mt)
                Ah[mt] = *(const short8*)((const unsigned short*)Ap +
                          (rowb + (mt << 4) + lm) * (size_t)K + kk + (lg << 3));
        } else {
            float g[8], bb[8];
            if (AMODE == 1) {
                float4 g0 = *(const float4*)(lng + kk + (lg << 3));
                float4 g1 = *(const float4*)(lng + kk + (lg << 3) + 4);
                float4 b0 = *(const float4*)(lnb + kk + (lg << 3));
                float4 b1 = *(const float4*)(lnb + kk + (lg << 3) + 4);
                g[0]=g0.x; g[1]=g0.y; g[2]=g0.z; g[3]=g0.w; g[4]=g1.x; g[5]=g1.y; g[6]=g1.z; g[7]=g1.w;
                bb[0]=b0.x; bb[1]=b0.y; bb[2]=b0.z; bb[3]=b0.w; bb[4]=b1.x; bb[5]=b1.y; bb[6]=b1.z; bb[7]=b1.w;
            }
            #pragma unroll
            for (int mt = 0; mt < 4; ++mt) {
                const float* ar = (const float*)Ap + (rowb + (mt << 4) + lm) * (size_t)K + kk + (lg << 3);
                float4 a0 = *(const float4*)ar;
                float4 a1 = *(const float4*)(ar + 4);
                float e[8] = {a0.x, a0.y, a0.z, a0.w, a1.x, a1.y, a1.z, a1.w};
                #pragma unroll
                for (int j = 0; j < 8; ++j) {
                    float v = e[j];
                    if (AMODE == 1) v = fmaf((v - lnm[mt]) * lnr[mt], g[j], bb[j]);
                    unsigned short h = f2bf(v);
                    Ah[mt][j] = (short)h;
                    Al[mt][j] = (short)f2bf(v - bf2f(h));
                }
            }
        }
        // ---- stage B tile [256 n][32 k] ----
        __syncthreads();
        {
            const unsigned short* gh = Bh + (size_t)nb * K + kk;
            #pragma unroll
            for (int it = 0; it < 4; ++it) {
                const int idx = (it << 8) + t;
                const int n = idx >> 2, sl = idx & 3;
                *(uint4*)&BhS[n][sl << 3] = *(const uint4*)(gh + (size_t)n * K + (sl << 3));
            }
            if (SPLIT) {
                const unsigned short* gl = Bl + (size_t)nb * K + kk;
                #pragma unroll
                for (int it = 0; it < 4; ++it) {
                    const int idx = (it << 8) + t;
                    const int n = idx >> 2, sl = idx & 3;
                    *(uint4*)&BlS[n][sl << 3] = *(const uint4*)(gl + (size_t)n * K + (sl << 3));
                }
            }
        }
        __syncthreads();
        // ---- MFMA: 4mt x 8nt ----
        #pragma unroll
        for (int nt = 0; nt < 8; ++nt) {
            const int nl = (wn << 7) + (nt << 4) + lm;
            short8 bh = *(const short8*)&BhS[nl][lg << 3];
            if (!SPLIT) {
                #pragma unroll
                for (int mt = 0; mt < 4; ++mt)
                    acc[mt][nt] = mfma_bf16(Ah[mt], bh, acc[mt][nt]);
            } else {
                short8 bl = *(const short8*)&BlS[nl][lg << 3];
                #pragma unroll
                for (int mt = 0; mt < 4; ++mt) {
                    acc[mt][nt] = mfma_bf16(Ah[mt], bh, acc[mt][nt]);
                    acc[mt][nt] = mfma_bf16(Al[mt], bh, acc[mt][nt]);
                    acc[mt][nt] = mfma_bf16(Ah[mt], bl, acc[mt][nt]);
                }
            }
        }
    }

    // ---- epilogue: C[row = rowb+mt*16+lg*4+r][col = nb+wn*128+nt*16+lm] ----
    float lsum = 0.0f;
    #pragma unroll
    for (int nt = 0; nt < 8; ++nt) {
        const int col = nb + (wn << 7) + (nt << 4) + lm;
        const float bs = bias[col];
        #pragma unroll
        for (int mt = 0; mt < 4; ++mt) {
            #pragma unroll
            for (int r = 0; r < 4; ++r) {
                float v = acc[mt][nt][r] + bs;
                if (EPI == 0 || EPI == 2) v = fmaxf(v, 0.0f);
                const size_t row = rowb + (mt << 4) + (lg << 2) + r;
                if (EPI == 2) {
                    ((unsigned short*)Cp)[row * Nc + col] = f2bf(v);
                } else {
                    ((float*)Cp)[row * Nc + col] = v;
                }
                if (EPI == 3) {
                    const float d = v - xref[row * Nc + col];
                    lsum = fmaf(d, d, lsum);
                }
            }
        }
    }
    if (EPI == 3) {
        #pragma unroll
        for (int o = 32; o > 0; o >>= 1) lsum += __shfl_xor(lsum, o);
        if (lane == 0) credsh[wave] = lsum;
        __syncthreads();
        if (t == 0) atomicAdd(acc_rec, (double)((credsh[0] + credsh[1]) + (credsh[2] + credsh[3])));
    }
}

// Fused 4-level residual quantization, MFMA bf16x2-split edition.
// Block = 256 thr = 4 waves; wave owns 32 rows (2 MFMA m-tiles) held entirely in
// registers as hi/lo bf16 A-fragments. Codebook hi/lo streamed through LDS in
// 32-code chunks. dist = ||c||^2 - 2*(r_hi.c_hi + r_lo.c_hi + r_hi.c_lo).
__global__ __launch_bounds__(256, 2) void k_quant_mfma(
    const float* __restrict__ enc, const float* __restrict__ cb,
    const unsigned short* __restrict__ cbh, const unsigned short* __restrict__ cbl,
    const float* __restrict__ cnorm, unsigned short* __restrict__ qf, float* __restrict__ oidx,
    int* __restrict__ flag, double* __restrict__ acc_commit)
{
    __shared__ unsigned short Bh[32][264];   // 32 codes x 256 k, pad 8 (2-way-free b128 reads)
    __shared__ unsigned short Bl[32][264];
    __shared__ __align__(16) int rowidxsh[128];
    __shared__ float credsh[4];

    const int t = threadIdx.x;
    const int wave = t >> 6, lane = t & 63;
    const int lg = lane >> 4, lm = lane & 15;
    const size_t rowbase = (size_t)blockIdx.x * 128 + wave * 32;

    // ---- load enc rows into hi/lo A-fragments (A[m=lane&15][k=lg*8+j], 8 k-steps) ----
    short8 Ah[2][8], Al[2][8];
    #pragma unroll
    for (int mt = 0; mt < 2; ++mt)
        #pragma unroll
        for (int s = 0; s < 8; ++s) {
            const float* er = enc + (rowbase + mt * 16 + lm) * ODIM + s * 32 + lg * 8;
            float4 e0 = *(const float4*)er;
            float4 e1 = *(const float4*)(er + 4);
            float e[8] = {e0.x, e0.y, e0.z, e0.w, e1.x, e1.y, e1.z, e1.w};
            #pragma unroll
            for (int j = 0; j < 8; ++j) {
                unsigned short h = f2bf(e[j]);
                Ah[mt][s][j] = (short)h;
                Al[mt][s][j] = (short)f2bf(e[j] - bf2f(h));
            }
        }

    float commit_local = 0.0f;
    int flg[2][4] = {{0, 0, 0, 0}, {0, 0, 0, 0}};

    for (int l = 0; l < NLEV; ++l) {
        const size_t lbase = (size_t)l * CBS * ODIM;
        float bestv[2][4], b2v[2][4];
        int besti[2][4];
        #pragma unroll
        for (int mt = 0; mt < 2; ++mt)
            #pragma unroll
            for (int r = 0; r < 4; ++r) { bestv[mt][r] = 3.4e38f; b2v[mt][r] = 3.4e38f; besti[mt][r] = 0; }

        for (int ch = 0; ch < 32; ++ch) {
            const int cbase = ch << 5;
            __syncthreads();
            // stage 32 codes of hi/lo codebook into LDS (coalesced 16B, padded rows)
            {
                const unsigned short* gh = cbh + lbase + (size_t)cbase * ODIM;
                const unsigned short* gl = cbl + lbase + (size_t)cbase * ODIM;
                #pragma unroll
                for (int r = 0; r < 4; ++r) {
                    const int i = (r << 8) + t;           // 0..1023 slots of 8 shorts
                    const int code = i >> 5, sl = i & 31;
                    *(uint4*)&Bh[code][sl << 3] = *(const uint4*)(gh + ((size_t)i << 3));
                    *(uint4*)&Bl[code][sl << 3] = *(const uint4*)(gl + ((size_t)i << 3));
                }
            }
            __syncthreads();
            #pragma unroll
            for (int nt = 0; nt < 2; ++nt) {
                f32x4 hh[2], lh[2], hl[2];
                #pragma unroll
                for (int mt = 0; mt < 2; ++mt) {
                    hh[mt] = (f32x4){0.f, 0.f, 0.f, 0.f};
                    lh[mt] = (f32x4){0.f, 0.f, 0.f, 0.f};
                    hl[mt] = (f32x4){0.f, 0.f, 0.f, 0.f};
                }
                #pragma unroll
                for (int s = 0; s < 8; ++s) {
                    short8 bh = *(const short8*)&Bh[(nt << 4) + lm][(s << 5) + (lg << 3)];
                    short8 bl = *(const short8*)&Bl[(nt << 4) + lm][(s << 5) + (lg << 3)];
                    hh[0] = mfma_bf16(Ah[0][s], bh, hh[0]);
                    hh[1] = mfma_bf16(Ah[1][s], bh, hh[1]);
                    lh[0] = mfma_bf16(Al[0][s], bh, lh[0]);
                    lh[1] = mfma_bf16(Al[1][s], bh, lh[1]);
                    hl[0] = mfma_bf16(Ah[0][s], bl, hl[0]);
                    hl[1] = mfma_bf16(Ah[1][s], bl, hl[1]);
                }
                const int code = cbase + (nt << 4) + lm;
                const float cn = cnorm[(l << 10) + code];
                #pragma unroll
                for (int mt = 0; mt < 2; ++mt)
                    #pragma unroll
                    for (int r = 0; r < 4; ++r) {
                        const float dot = hh[mt][r] + lh[mt][r] + hl[mt][r];
                        const float d = fmaf(-2.0f, dot, cn);
                        if (d < bestv[mt][r]) {
                            b2v[mt][r] = bestv[mt][r]; bestv[mt][r] = d; besti[mt][r] = code;
                        } else {
                            b2v[mt][r] = fminf(b2v[mt][r], d);
                        }
                    }
            }
        }

        // ---- cross-lane argmin over the 16 C-columns (xor butterfly in low 4 lane bits) ----
        #pragma unroll
        for (int mt = 0; mt < 2; ++mt) {
            int iv[4];
            #pragma unroll
            for (int r = 0; r < 4; ++r) {
                float bv = bestv[mt][r], b2 = b2v[mt][r];
                int bi = besti[mt][r];
                #pragma unroll
                for (int off = 1; off < 16; off <<= 1) {
                    float ov = __shfl_xor(bv, off);
                    float o2 = __shfl_xor(b2, off);
                    int   oi = __shfl_xor(bi, off);
                    if (ov < bv)      { b2 = fminf(bv, o2); bv = ov; bi = oi; }
                    else if (ov > bv) { b2 = fminf(b2, ov); }
                    else              { b2 = bv; bi = (oi < bi) ? oi : bi; }
                }
                flg[mt][r] |= (b2 - bv < TAUQ) ? 1 : 0;
                iv[r] = bi;
                if (lm == 0)
                    oidx[(rowbase + (mt << 4) + (lg << 2) + r) * NLEV + l] = (float)bi;
            }
            if (lm == 0)
                *(int4*)&rowidxsh[(wave << 5) + (mt << 4) + (lg << 2)] = make_int4(iv[0], iv[1], iv[2], iv[3]);
        }
        __syncthreads();

        // ---- residual update in registers: r -= cb[best]; commit += r^2; re-split ----
        #pragma unroll
        for (int mt = 0; mt < 2; ++mt) {
            const int ci = rowidxsh[(wave << 5) + (mt << 4) + lm];
            const float* cr = cb + lbase + (size_t)ci * ODIM + lg * 8;
            #pragma unroll
            for (int s = 0; s < 8; ++s) {
                float4 c0 = *(const float4*)(cr + (s << 5));
                float4 c1 = *(const float4*)(cr + (s << 5) + 4);
                float c[8] = {c0.x, c0.y, c0.z, c0.w, c1.x, c1.y, c1.z, c1.w};
                #pragma unroll
                for (int j = 0; j < 8; ++j) {
                    float rr = bf2f((unsigned short)Ah[mt][s][j]) + bf2f((unsigned short)Al[mt][s][j]) - c[j];
                    commit_local = fmaf(rr, rr, commit_local);
                    unsigned short h = f2bf(rr);
                    Ah[mt][s][j] = (short)h;
                    Al[mt][s][j] = (short)f2bf(rr - bf2f(h));
                }
            }
        }
    }

    // ---- q_final = enc - r_final, stored bf16 for the MFMA decoder ----
    #pragma unroll
    for (int mt = 0; mt < 2; ++mt)
        #pragma unroll
        for (int s = 0; s < 8; ++s) {
            const size_t ro = (rowbase + mt * 16 + lm) * ODIM + s * 32 + lg * 8;
            float4 e0 = *(const float4*)(enc + ro);
            float4 e1 = *(const float4*)(enc + ro + 4);
            float e[8] = {e0.x, e0.y, e0.z, e0.w, e1.x, e1.y, e1.z, e1.w};
            unsigned short q[8];
            #pragma unroll
            for (int j = 0; j < 8; ++j)
                q[j] = f2bf(e[j] - (bf2f((unsigned short)Ah[mt][s][j]) + bf2f((unsigned short)Al[mt][s][j])));
            *(ushort4*)(qf + ro)     = make_ushort4(q[0], q[1], q[2], q[3]);
            *(ushort4*)(qf + ro + 4) = make_ushort4(q[4], q[5], q[6], q[7]);
        }

    if (lm == 0) {
        #pragma unroll
        for (int mt = 0; mt < 2; ++mt)
            #pragma unroll
            for (int r = 0; r < 4; ++r)
                flag[rowbase + (mt << 4) + (lg << 2) + r] = flg[mt][r];
    }

    #pragma unroll
    for (int o = 32; o > 0; o >>= 1) commit_local += __shfl_xor(commit_local, o);
    if (lane == 0) credsh[wave] = commit_local;
    __syncthreads();
    if (t == 0) atomicAdd(acc_commit, (double)((credsh[0] + credsh[1]) + (credsh[2] + credsh[3])));
}

// f64 exact recompute of the index chain for flagged (near-tie) rows.
__global__ __launch_bounds__(256) void k_fix(
    const int* __restrict__ flag, const float* __restrict__ x,
    const float* __restrict__ lng, const float* __restrict__ lnb,
    const float* __restrict__ W1, const float* __restrict__ b1,
    const float* __restrict__ W2, const float* __restrict__ b2,
    const float* __restrict__ cb, float* __restrict__ oidx)
{
    const int row = blockIdx.x;
    if (!flag[row]) return;
    const int t = threadIdx.x;
    __shared__ double xn[INDIM];
    __shared__ double hs[ODIM];
    __shared__ double r[ODIM];
    __shared__ double rv_[4];
    __shared__ int ri_[4];
    __shared__ int selidx;

    const float* xr = x + (size_t)row * INDIM;
    double xa = (double)xr[t], xb = (double)xr[t + 256], xc = (double)xr[t + 512];
    double s1 = xa + xb + xc;
    double s2 = xa * xa + xb * xb + xc * xc;
    #pragma unroll
    for (int o = 32; o > 0; o >>= 1) { s1 += __shfl_xor(s1, o); s2 += __shfl_xor(s2, o); }
    __shared__ double w1r[4], w2r[4];
    if ((t & 63) == 0) { w1r[t >> 6] = s1; w2r[t >> 6] = s2; }
    __syncthreads();
    double S1 = (w1r[0] + w1r[1]) + (w1r[2] + w1r[3]);
    double S2 = (w2r[0] + w2r[1]) + (w2r[2] + w2r[3]);
    double mu = S1 / (double)INDIM;
    double var = S2 / (double)INDIM - mu * mu;
    double rs = 1.0 / sqrt(var + 1e-5);
    xn[t]       = (xa - mu) * rs * (double)lng[t]       + (double)lnb[t];
    xn[t + 256] = (xb - mu) * rs * (double)lng[t + 256] + (double)lnb[t + 256];
    xn[t + 512] = (xc - mu) * rs * (double)lng[t + 512] + (double)lnb[t + 512];
    __syncthreads();
    double h = (double)b1[t];
    for (int k = 0; k < INDIM; ++k) h += xn[k] * (double)W1[(size_t)k * ODIM + t];
    hs[t] = fmax(h, 0.0);
    __syncthreads();
    double e = (double)b2[t];
    for (int k = 0; k < ODIM; ++k) e += hs[k] * (double)W2[(size_t)k * ODIM + t];
    r[t] = e;
    __syncthreads();

    for (int l = 0; l < NLEV; ++l) {
        const float* cbl = cb + (size_t)l * CBS * ODIM;
        double bv = 1e300; int bi = 0;
        #pragma unroll
        for (int j = 0; j < 4; ++j) {
            const int code = t * 4 + j;
            const float* cr = cbl + (size_t)code * ODIM;
            double d = 0.0;
            for (int k = 0; k < ODIM; k += 4) {
                float4 c4 = *(const float4*)(cr + k);
                double d0 = r[k + 0] - (double)c4.x;
                double d1 = r[k + 1] - (double)c4.y;
                double d2 = r[k + 2] - (double)c4.z;
                double d3 = r[k + 3] - (double)c4.w;
                d += d0 * d0 + d1 * d1 + d2 * d2 + d3 * d3;
            }
            if (d < bv || (d == bv && code < bi)) { bv = d; bi = code; }
        }
        #pragma unroll
        for (int o = 32; o > 0; o >>= 1) {
            double ov = __shfl_xor(bv, o);
            int oi = __shfl_xor(bi, o);
            if (ov < bv || (ov == bv && oi < bi)) { bv = ov; bi = oi; }
        }
        if ((t & 63) == 0) { rv_[t >> 6] = bv; ri_[t >> 6] = bi; }
        __syncthreads();
        if (t == 0) {
            double fv = rv_[0]; int fi = ri_[0];
            #pragma unroll
            for (int w = 1; w < 4; ++w)
                if (rv_[w] < fv || (rv_[w] == fv && ri_[w] < fi)) { fv = rv_[w]; fi = ri_[w]; }
            selidx = fi;
            oidx[(size_t)row * NLEV + l] = (float)fi;
        }
        __syncthreads();
        r[t] = r[t] - (double)cb[(size_t)l * CBS * ODIM + (size_t)selidx * ODIM + t];
        __syncthreads();
    }
}

__global__ void k_fin(const double* __restrict__ acc, float* __restrict__ out) {
    if (threadIdx.x == 0)
        out[0] = (float)(acc[1] / ((double)NROWS * (double)INDIM) +
                         0.25 * (acc[0] / ((double)NROWS * (double)ODIM)));
}

extern "C" void kernel_launch(void* const* d_in, const int* in_sizes, int n_in,
                              void* d_out, int out_size, void* d_ws, size_t ws_size,
                              hipStream_t stream)
{
    const float* x   = (const float*)d_in[0];
    const float* lng = (const float*)d_in[1];
    const float* lnb = (const float*)d_in[2];
    const float* W1  = (const float*)d_in[3];
    const float* b1  = (const float*)d_in[4];
    const float* W2  = (const float*)d_in[5];
    const float* b2  = (const float*)d_in[6];
    const float* Wd1 = (const float*)d_in[7];
    const float* bd1 = (const float*)d_in[8];
    const float* Wd2 = (const float*)d_in[9];
    const float* bd2 = (const float*)d_in[10];
    const float* cbs = (const float*)d_in[11];

    char* ws = (char*)d_ws;
    const size_t MB = 1u << 20;
    const size_t O_ACC  = 0;
    const size_t O_CN   = 1024;
    const size_t O_MU   = O_CN + 16384;
    const size_t O_RS   = O_MU + (size_t)NROWS * 4;
    const size_t O_FLAG = O_RS + (size_t)NROWS * 4;
    const size_t O_ENC  = 1 * MB;                 // 64 MB f32
    const size_t O_QF   = 65 * MB;                // 32 MB bf16
    const size_t O_W1H  = 97 * MB;                // transposed weights, ~2.5 MB total
    const size_t O_W1L  = O_W1H + (size_t)INDIM * ODIM * 2;
    const size_t O_W2H  = O_W1L + (size_t)INDIM * ODIM * 2;
    const size_t O_W2L  = O_W2H + (size_t)ODIM * ODIM * 2;
    const size_t O_WD1  = O_W2L + (size_t)ODIM * ODIM * 2;
    const size_t O_WD2  = O_WD1 + (size_t)ODIM * INDIM * 2;
    const size_t O_CBH  = 100 * MB;               // 2 MB
    const size_t O_CBL  = 102 * MB;               // 2 MB
    const size_t O_H1   = 104 * MB;               // h1 f32 64 MB, later aliased by hd bf16 100 MB

    double* acc   = (double*)(ws + O_ACC);   // [0]=commit sum, [1]=rec sum
    float* cnorm  = (float*)(ws + O_CN);
    float* mu     = (float*)(ws + O_MU);
    float* rsig   = (float*)(ws + O_RS);
    int*   flag   = (int*)(ws + O_FLAG);
    float* enc    = (float*)(ws + O_ENC);
    unsigned short* qf  = (unsigned short*)(ws + O_QF);
    unsigned short* w1h = (unsigned short*)(ws + O_W1H);
    unsigned short* w1l = (unsigned short*)(ws + O_W1L);
    unsigned short* w2h = (unsigned short*)(ws + O_W2H);
    unsigned short* w2l = (unsigned short*)(ws + O_W2L);
    unsigned short* wd1h = (unsigned short*)(ws + O_WD1);
    unsigned short* wd2h = (unsigned short*)(ws + O_WD2);
    unsigned short* cbh = (unsigned short*)(ws + O_CBH);
    unsigned short* cbl = (unsigned short*)(ws + O_CBL);
    float* h1     = (float*)(ws + O_H1);
    unsigned short* hd = (unsigned short*)(ws + O_H1);

    float* outF  = (float*)d_out;
    float* recon = outF + 1;
    float* oidx  = outF + 1 + (size_t)NROWS * INDIM;

    k_init<<<1, 64, 0, stream>>>(acc);
    k_cnorm<<<NLEV * CBS, 64, 0, stream>>>(cbs, cnorm);
    k_ln<<<NROWS, 256, 0, stream>>>(x, mu, rsig);
    // weight transpose + bf16(x2) conversion
    k_wt<<<ODIM, 256, 0, stream>>>(W1, w1h, w1l, INDIM, ODIM, 1);
    k_wt<<<ODIM, 256, 0, stream>>>(W2, w2h, w2l, ODIM, ODIM, 1);
    k_wt<<<INDIM, 256, 0, stream>>>(Wd1, wd1h, nullptr, ODIM, INDIM, 0);
    k_wt<<<INDIM, 256, 0, stream>>>(Wd2, wd2h, nullptr, INDIM, INDIM, 0);
    k_split<<<(NLEV * CBS * ODIM) / 1024, 256, 0, stream>>>(cbs, cbh, cbl);
    // encoder: LN(x)@W1 relu -> h1;  h1@W2 -> enc   (bf16x2-split MFMA)
    k_gemm_mfma<1, 1, 0><<<dim3(1, NROWS / 128), 256, 0, stream>>>(
        x, w1h, w1l, b1, h1, INDIM, ODIM, mu, rsig, lng, lnb, nullptr, nullptr);
    k_gemm_mfma<0, 1, 1><<<dim3(1, NROWS / 128), 256, 0, stream>>>(
        h1, w2h, w2l, b2, enc, ODIM, ODIM, nullptr, nullptr, nullptr, nullptr, nullptr, nullptr);
    // residual quantization: MFMA bf16x2-split + near-tie flags, qf out bf16
    k_quant_mfma<<<NROWS / 128, 256, 0, stream>>>(enc, cbs, cbh, cbl, cnorm, qf, oidx, flag, acc);
    // f64 exact index fix for flagged rows
    k_fix<<<NROWS, 256, 0, stream>>>(flag, x, lng, lnb, W1, b1, W2, b2, cbs, oidx);
    // decoder: qf@Wd1 relu -> hd (bf16);  hd@Wd2 -> recon + rec_loss   (plain bf16 MFMA)
    k_gemm_mfma<2, 0, 2><<<dim3(INDIM / 256, NROWS / 128), 256, 0, stream>>>(
        qf, wd1h, nullptr, bd1, hd, ODIM, INDIM, nullptr, nullptr, nullptr, nullptr, nullptr, nullptr);
    k_gemm_mfma<2, 0, 3><<<dim3(INDIM / 256, NROWS / 128), 256, 0, stream>>>(
        hd, wd2h, nullptr, bd2, recon, INDIM, INDIM, nullptr, nullptr, nullptr, nullptr, x, acc + 1);
    k_fin<<<1, 64, 0, stream>>>(acc, outF);
}